// Round 10
// baseline (3339.336 us; speedup 1.0000x reference)
//
#include <hip/hip_runtime.h>
#include <hip/hip_bf16.h>
#include <stdint.h>
#include <stddef.h>

typedef __hip_bfloat16 bf16;
typedef __attribute__((ext_vector_type(8))) short bfrag;
typedef __attribute__((ext_vector_type(4))) float ffrag;
typedef unsigned long long u64;

#define HDIM 1024
#define BATCH 64
#define TSTEPS 256
#define GDIM 4096
#define VOCAB 32000

// xg (layer1): ((q*128 + g)*16384 + b*256 + t)*8 + jj   (g = hidden-col octet, jj = col&7)
// h-history: 257 slots x 128 KB; slot (256-t) = h INPUT to step t (write-once).
//   within slot (u64): half*8192 + kg*64 + b  (col = kg*8 + half*4 + jj, jj=col&3)
#define HSLOT 16384ull

__device__ __forceinline__ bf16 f2b(float x) { return __float2bfloat16(x); }
__device__ __forceinline__ short f2bs(float x) {
  bf16 b = __float2bfloat16(x);
  return *reinterpret_cast<short*>(&b);
}
__device__ __forceinline__ float bs2f(unsigned short u) {
  union { unsigned int i; float f; } v;
  v.i = ((unsigned int)u) << 16;
  return v.f;
}
__device__ __forceinline__ ffrag mfma16(bfrag a, bfrag b, ffrag c) {
  return __builtin_amdgcn_mfma_f32_16x16x32_bf16(a, b, c, 0, 0, 0);
}
__device__ __forceinline__ float sigm(float x) { return 1.0f / (1.0f + __expf(-x)); }
__device__ __forceinline__ float tanhfast(float x) {
  float e = __expf(2.0f * x);
  return 1.0f - 2.0f / (e + 1.0f);
}

__device__ __forceinline__ void store_u16_agent(unsigned short* p, unsigned short v) {
  __hip_atomic_store(p, v, __ATOMIC_RELAXED, __HIP_MEMORY_SCOPE_AGENT);
}
__device__ __forceinline__ u64 load_u64_agent(const u64* p) {
  return __hip_atomic_load(p, __ATOMIC_RELAXED, __HIP_MEMORY_SCOPE_AGENT);
}
__device__ __forceinline__ void store_u32_agent(unsigned* p, unsigned v) {
  __hip_atomic_store(p, v, __ATOMIC_RELAXED, __HIP_MEMORY_SCOPE_AGENT);
}

// ---------------- convert f32 -> bf16 ----------------
__global__ void convert_bf16_kernel(const float* __restrict__ src, bf16* __restrict__ dst, int n4) {
  int i = blockIdx.x * 256 + threadIdx.x;
  if (i >= n4) return;
  float4 v = reinterpret_cast<const float4*>(src)[i];
  ushort4 o;
  o.x = (unsigned short)f2bs(v.x);
  o.y = (unsigned short)f2bs(v.y);
  o.z = (unsigned short)f2bs(v.z);
  o.w = (unsigned short)f2bs(v.w);
  reinterpret_cast<ushort4*>(dst)[i] = o;
}

// ---------------- embedding gather -> bf16 (rows m = b*256 + t) ----------------
__global__ void embed_kernel(const int* __restrict__ ids, const float* __restrict__ table,
                             bf16* __restrict__ x, int n4) {
  int i = blockIdx.x * 256 + threadIdx.x;
  if (i >= n4) return;
  int row = i >> 8;
  int c4 = i & 255;
  int tok = ids[row];
  float4 v = reinterpret_cast<const float4*>(table)[(size_t)tok * 256 + c4];
  ushort4 o;
  o.x = (unsigned short)f2bs(v.x);
  o.y = (unsigned short)f2bs(v.y);
  o.z = (unsigned short)f2bs(v.z);
  o.w = (unsigned short)f2bs(v.w);
  reinterpret_cast<ushort4*>(x)[i] = o;
}

// ---------------- xg1 = x @ W_ih1^T + b_ih1 + b_hh1 ----------------
#define BMX 128
#define BNX 128
#define BKX 64

__launch_bounds__(256, 2)
__global__ void gemm_xg_kernel(const bf16* __restrict__ A,
                               const bf16* __restrict__ W,
                               const float* __restrict__ bih,
                               const float* __restrict__ bhh,
                               bf16* __restrict__ xg) {
  __shared__ bf16 As[BMX][BKX + 8];
  __shared__ bf16 Bs[BNX][BKX + 8];
  const int n0 = blockIdx.x * BNX;
  const int m0 = blockIdx.y * BMX;
  const int tid = threadIdx.x;
  const int w = tid >> 6, l = tid & 63;
  const int wm = (w >> 1) * 64, wn = (w & 1) * 64;
  const int lr = l & 15, lk = (l >> 4) * 8;

  ffrag acc[4][4];
#pragma unroll
  for (int i = 0; i < 4; ++i)
#pragma unroll
    for (int j = 0; j < 4; ++j) acc[i][j] = ffrag{0.f, 0.f, 0.f, 0.f};

  const int sr = tid >> 1, sh = (tid & 1) * 32;
  for (int kb = 0; kb < HDIM; kb += BKX) {
    __syncthreads();
    {
      const uint4* ga = reinterpret_cast<const uint4*>(&A[(size_t)(m0 + sr) * HDIM + kb + sh]);
      uint4* la = reinterpret_cast<uint4*>(&As[sr][sh]);
      la[0] = ga[0]; la[1] = ga[1]; la[2] = ga[2]; la[3] = ga[3];
      const uint4* gb = reinterpret_cast<const uint4*>(&W[(size_t)(n0 + sr) * HDIM + kb + sh]);
      uint4* lb = reinterpret_cast<uint4*>(&Bs[sr][sh]);
      lb[0] = gb[0]; lb[1] = gb[1]; lb[2] = gb[2]; lb[3] = gb[3];
    }
    __syncthreads();
#pragma unroll
    for (int ks = 0; ks < 2; ++ks) {
      const int ko = ks * 32 + lk;
      bfrag af[4], bfv[4];
#pragma unroll
      for (int i = 0; i < 4; ++i)
        af[i] = *reinterpret_cast<const bfrag*>(&As[wm + i * 16 + lr][ko]);
#pragma unroll
      for (int j = 0; j < 4; ++j)
        bfv[j] = *reinterpret_cast<const bfrag*>(&Bs[wn + j * 16 + lr][ko]);
#pragma unroll
      for (int i = 0; i < 4; ++i)
#pragma unroll
        for (int j = 0; j < 4; ++j)
          acc[i][j] = mfma16(af[i], bfv[j], acc[i][j]);
    }
  }
  const int rg = (l >> 4) * 4;
#pragma unroll
  for (int j = 0; j < 4; ++j) {
    const int n = n0 + wn + j * 16 + lr;
    const float bias = bih[n] + bhh[n];
    const int q = n >> 10, g = (n & 1023) >> 3, jj = n & 7;
    bf16* base = xg + (size_t)(q * 128 + g) * 16384 * 8 + jj;
#pragma unroll
    for (int i = 0; i < 4; ++i) {
#pragma unroll
      for (int r = 0; r < 4; ++r) {
        const int m = m0 + wm + i * 16 + rg + r;   // m = b*256 + t
        base[(size_t)m * 8] = f2b(acc[i][j][r] + bias);
      }
    }
  }
}

// ---------------- fused 2-layer pipelined LSTM ----------------
// 768 blocks x 256 thr (4 waves), __launch_bounds__(256,3) -> 3 blocks/CU co-resident.
// ids 0..255:  L1 recurrence. Block (bg=id&3, cg16=id>>2): 16 batches x 16 hidden cols.
//   Waves (kh=K-half, ch=col-half of 8): 2 B-tiles x 16 ks = 32 W_hh1 bfrags in regs.
// ids 256..767: L2 recurrence WITH fused x-projection. Block (bg, cg8): 16 b x 8 cols.
//   Waves (kh, ch4=col-half of 4): 1 tile x 16 ks x {W_hh2, W_ih2} = 32 bfrags in regs.
//   Per step s: acc = y1(s)@Wih2 + h2(s)@Whh2 chained into one accumulator.
// L2 trails L1 by 1 step; if L2 blocks are not all resident the pipeline degrades
// to sequential (L1 retires -> L2 proceeds) -- no deadlock.
__launch_bounds__(256, 3)
__global__ void fused2_kernel(const bf16* __restrict__ xg,
                              const bf16* __restrict__ whh1,
                              const bf16* __restrict__ whh2,
                              const bf16* __restrict__ wih2,
                              const float* __restrict__ bih2,
                              const float* __restrict__ bhh2,
                              bf16* histA, bf16* histB,
                              float* __restrict__ out_h1, float* __restrict__ out_c1,
                              float* __restrict__ out_h2, float* __restrict__ out_c2,
                              float* __restrict__ out_last,
                              unsigned* __restrict__ fL1,
                              unsigned* __restrict__ fL2) {
  __shared__ float gxp[2][16][65];
  const int id = blockIdx.x;
  const int tid = threadIdx.x;
  const int w = tid >> 6, l = tid & 63;
  const int lr = l & 15, lkg = l >> 4;
  const int kh = w >> 1;
  const int q = lr >> 2, jn = lr & 3;

  if (id < 256) {
    // ================= Layer-1 =================
    const int bg = id & 3, cg16 = id >> 2;
    const int ch = w & 1;
    bfrag breg0[16], breg1[16];
    {
      const int colbase = cg16 * 16 + ch * 8;
      const size_t r0 = ((size_t)q * HDIM + colbase + jn) * HDIM + kh * 512 + lkg * 8;
      const size_t r1 = ((size_t)q * HDIM + colbase + 4 + jn) * HDIM + kh * 512 + lkg * 8;
#pragma unroll
      for (int ks = 0; ks < 16; ++ks) {
        breg0[ks] = *reinterpret_cast<const bfrag*>(&whh1[r0 + ks * 32]);
        breg1[ks] = *reinterpret_cast<const bfrag*>(&whh1[r1 + ks * 32]);
      }
    }
    // elementwise identity (all 256 threads): batch eb, col-local cl
    const int eb = tid & 15, cl = tid >> 4;
    const int gpl = cg16 * 2 + (cl >> 3);   // xg plane
    const int xjj = cl & 7;
    const int kgs = cg16 * 2 + (cl >> 3);   // h-store kg
    const int shalf = (cl >> 2) & 1, sjj = cl & 3;
    float c = 0.0f;

    u64* hb = (u64*)histA;
    const size_t arow = (size_t)(kh * 64 + lkg) * 64 + bg * 16 + lr;
    const u64* fv = (const u64*)fL1 + (size_t)bg * 128;
    const unsigned short* xgu = (const unsigned short*)xg;

    unsigned short xn[4];
#pragma unroll
    for (int qq = 0; qq < 4; ++qq)
      xn[qq] = xgu[(((size_t)qq * 128 + gpl) * 16384 + (size_t)(bg * 16 + eb) * 256) * 8 + xjj];

#pragma unroll 1
    for (int t = 0; t < TSTEPS; ++t) {
      if (t > 0) {
        const unsigned tt = (unsigned)t;
        for (;;) {
          u64 fa = load_u64_agent(&fv[l]);
          u64 fb = load_u64_agent(&fv[64 + l]);
          int ok = ((unsigned)fa >= tt) && ((unsigned)(fa >> 32) >= tt) &&
                   ((unsigned)fb >= tt) && ((unsigned)(fb >> 32) >= tt);
          if (__all(ok)) break;
          __builtin_amdgcn_s_sleep(1);
        }
      }
      __builtin_amdgcn_sched_barrier(0);
      asm volatile("" ::: "memory");

      const u64* hin = hb + (size_t)(TSTEPS - t) * HSLOT;
      ffrag a0 = ffrag{0.f, 0.f, 0.f, 0.f};
      ffrag a1 = ffrag{0.f, 0.f, 0.f, 0.f};
#pragma unroll
      for (int ks = 0; ks < 16; ++ks) {
        union { u64 u[2]; bfrag f; } au;
        au.u[0] = hin[arow + ks * 256];
        au.u[1] = hin[8192 + arow + ks * 256];
        a0 = mfma16(au.f, breg0[ks], a0);
        a1 = mfma16(au.f, breg1[ks], a1);
      }
      {
        const int cb = (w & 1) * 8;
#pragma unroll
        for (int r = 0; r < 4; ++r) {
          gxp[kh][lkg * 4 + r][q * 16 + cb + jn]     = a0[r];
          gxp[kh][lkg * 4 + r][q * 16 + cb + 4 + jn] = a1[r];
        }
      }
      __syncthreads();

      const float gi = gxp[0][eb][cl]      + gxp[1][eb][cl]      + bs2f(xn[0]);
      const float gf = gxp[0][eb][16 + cl] + gxp[1][eb][16 + cl] + bs2f(xn[1]);
      const float gg = gxp[0][eb][32 + cl] + gxp[1][eb][32 + cl] + bs2f(xn[2]);
      const float go = gxp[0][eb][48 + cl] + gxp[1][eb][48 + cl] + bs2f(xn[3]);
      c = sigm(gf) * c + sigm(gi) * tanhfast(gg);
      const float h = sigm(go) * tanhfast(c);

      u64* hout = hb + (size_t)(255 - t) * HSLOT;
      store_u16_agent((unsigned short*)(hout + (size_t)shalf * 8192 + kgs * 64 + bg * 16 + eb) + sjj,
                      (unsigned short)f2bs(h));
      if (t == TSTEPS - 1) {
        const int col = cg16 * 16 + cl;
        out_h1[(size_t)(bg * 16 + eb) * HDIM + col] = h;
        out_c1[(size_t)(bg * 16 + eb) * HDIM + col] = c;
      }
      __builtin_amdgcn_s_waitcnt(0);
      if (l == 0) store_u32_agent(&fL1[bg * 256 + cg16 * 4 + w], (unsigned)(t + 1));
      if (t < TSTEPS - 1) {
#pragma unroll
        for (int qq = 0; qq < 4; ++qq)
          xn[qq] = xgu[(((size_t)qq * 128 + gpl) * 16384 +
                        (size_t)(bg * 16 + eb) * 256 + t + 1) * 8 + xjj];
      }
      __syncthreads();
      __builtin_amdgcn_sched_barrier(0);
    }
  } else {
    // ================= Layer-2 (h-GEMM + fused y-GEMM) =================
    const int sid = id - 256;
    const int bg = sid & 3, cg8 = sid >> 2;
    const int ch4 = w & 1;
    bfrag wregH[16], wregY[16];
    {
      const int colbase = cg8 * 8 + ch4 * 4;
      const size_t rr = ((size_t)q * HDIM + colbase + jn) * HDIM + kh * 512 + lkg * 8;
#pragma unroll
      for (int ks = 0; ks < 16; ++ks) {
        wregH[ks] = *reinterpret_cast<const bfrag*>(&whh2[rr + ks * 32]);
        wregY[ks] = *reinterpret_cast<const bfrag*>(&wih2[rr + ks * 32]);
      }
    }
    const int eb = tid & 15, jc = tid >> 4;   // elementwise (tid<128): jc 0..7
    float biasq[4];
    if (tid < 128) {
#pragma unroll
      for (int qq = 0; qq < 4; ++qq) {
        const int n = qq * HDIM + cg8 * 8 + jc;
        biasq[qq] = bih2[n] + bhh2[n];
      }
    }
    float c = 0.0f;

    const u64* hbA = (const u64*)histA;
    u64* hbB = (u64*)histB;
    const size_t arow = (size_t)(kh * 64 + lkg) * 64 + bg * 16 + lr;
    const u64* f1 = (const u64*)fL1 + (size_t)bg * 128;
    const u64* f2d = (const u64*)fL2 + (size_t)bg * 64;

#pragma unroll 1
    for (int s = 0; s < TSTEPS; ++s) {
      {
        const unsigned tt = (unsigned)(s + 1);   // need L1 step s done
        for (;;) {
          u64 fa = load_u64_agent(&f1[l]);
          u64 fb = load_u64_agent(&f1[64 + l]);
          int ok = ((unsigned)fa >= tt) && ((unsigned)(fa >> 32) >= tt) &&
                   ((unsigned)fb >= tt) && ((unsigned)(fb >> 32) >= tt);
          if (__all(ok)) break;
          __builtin_amdgcn_s_sleep(2);
        }
      }
      if (s > 0) {
        const unsigned tt = (unsigned)s;         // own-domain h2(s-1) done
        for (;;) {
          u64 v = load_u64_agent(&f2d[l]);
          int ok = ((unsigned)v >= tt) && ((unsigned)(v >> 32) >= tt);
          if (__all(ok)) break;
          __builtin_amdgcn_s_sleep(1);
        }
      }
      __builtin_amdgcn_sched_barrier(0);
      asm volatile("" ::: "memory");

      const u64* yin = hbA + (size_t)(255 - s) * HSLOT;   // y1(s)
      const u64* hin = hbB + (size_t)(256 - s) * HSLOT;   // h2(s)
      ffrag acc = ffrag{0.f, 0.f, 0.f, 0.f};
#pragma unroll
      for (int ks = 0; ks < 16; ++ks) {
        union { u64 u[2]; bfrag f; } au;
        au.u[0] = yin[arow + ks * 256];
        au.u[1] = yin[8192 + arow + ks * 256];
        acc = mfma16(au.f, wregY[ks], acc);
      }
#pragma unroll
      for (int ks = 0; ks < 16; ++ks) {
        union { u64 u[2]; bfrag f; } au;
        au.u[0] = hin[arow + ks * 256];
        au.u[1] = hin[8192 + arow + ks * 256];
        acc = mfma16(au.f, wregH[ks], acc);
      }
#pragma unroll
      for (int r = 0; r < 4; ++r)
        gxp[kh][lkg * 4 + r][q * 8 + ch4 * 4 + jn] = acc[r];
      __syncthreads();

      if (tid < 128) {
        const float gi = gxp[0][eb][jc]      + gxp[1][eb][jc]      + biasq[0];
        const float gf = gxp[0][eb][8 + jc]  + gxp[1][eb][8 + jc]  + biasq[1];
        const float gg = gxp[0][eb][16 + jc] + gxp[1][eb][16 + jc] + biasq[2];
        const float go = gxp[0][eb][24 + jc] + gxp[1][eb][24 + jc] + biasq[3];
        c = sigm(gf) * c + sigm(gi) * tanhfast(gg);
        const float h = sigm(go) * tanhfast(c);
        u64* hout = hbB + (size_t)(255 - s) * HSLOT;
        store_u16_agent((unsigned short*)(hout + (size_t)(jc >> 2) * 8192 + cg8 * 64 + bg * 16 + eb) +
                            (jc & 3),
                        (unsigned short)f2bs(h));
        if (s == TSTEPS - 1) {
          const int col = cg8 * 8 + jc;
          out_h2[(size_t)(bg * 16 + eb) * HDIM + col] = h;
          out_c2[(size_t)(bg * 16 + eb) * HDIM + col] = c;
          out_last[(size_t)(bg * 16 + eb) * HDIM + col] = h;
        }
        __builtin_amdgcn_s_waitcnt(0);
      }
      __syncthreads();
      if (tid == 0) store_u32_agent(&fL2[bg * 128 + cg8], (unsigned)(s + 1));
      __builtin_amdgcn_sched_barrier(0);
    }
  }
}

// ---------------- logits = h_T @ W_proj^T + b_proj ----------------
__launch_bounds__(256, 2)
__global__ void logits_kernel(const bf16* __restrict__ hfin,
                              const float* __restrict__ Wp,
                              const float* __restrict__ bp,
                              float* __restrict__ out) {
  const int tid = threadIdx.x;
  const int w = tid >> 6, l = tid & 63;
  const int lr = l & 15, lkg = l >> 4, lk = lkg * 8;
  const int col = blockIdx.x * 64 + w * 16 + lr;
  const float* wrow = &Wp[(size_t)col * HDIM];
  const u64* hb = (const u64*)hfin;
  ffrag acc[4];
#pragma unroll
  for (int i = 0; i < 4; ++i) acc[i] = ffrag{0.f, 0.f, 0.f, 0.f};
#pragma unroll 2
  for (int ks = 0; ks < 32; ++ks) {
    const int k = ks * 32 + lk;
    float4 wa = *reinterpret_cast<const float4*>(&wrow[k]);
    float4 wb = *reinterpret_cast<const float4*>(&wrow[k + 4]);
    bfrag bv;
    bv[0] = f2bs(wa.x); bv[1] = f2bs(wa.y); bv[2] = f2bs(wa.z); bv[3] = f2bs(wa.w);
    bv[4] = f2bs(wb.x); bv[5] = f2bs(wb.y); bv[6] = f2bs(wb.z); bv[7] = f2bs(wb.w);
    const size_t kg = (size_t)(ks * 4 + lkg);
#pragma unroll
    for (int i = 0; i < 4; ++i) {
      union { u64 u[2]; bfrag f; } av;
      av.u[0] = hb[kg * 64 + i * 16 + lr];
      av.u[1] = hb[8192 + kg * 64 + i * 16 + lr];
      acc[i] = mfma16(av.f, bv, acc[i]);
    }
  }
  const float bias = bp[col];
#pragma unroll
  for (int i = 0; i < 4; ++i) {
#pragma unroll
    for (int r = 0; r < 4; ++r) {
      const int b = i * 16 + (l >> 4) * 4 + r;
      out[(size_t)b * VOCAB + col] = acc[i][r] + bias;
    }
  }
}

extern "C" void kernel_launch(void* const* d_in, const int* in_sizes, int n_in,
                              void* d_out, int out_size, void* d_ws, size_t ws_size,
                              hipStream_t stream) {
  const int*   ids   = (const int*)d_in[0];
  const float* table = (const float*)d_in[1];
  const float* Wih   = (const float*)d_in[2];
  const float* Whh   = (const float*)d_in[3];
  const float* bih   = (const float*)d_in[4];
  const float* bhh   = (const float*)d_in[5];
  const float* Wp    = (const float*)d_in[6];
  const float* bp    = (const float*)d_in[7];
  float* out = (float*)d_out;

  char* ws = (char*)d_ws;
  const size_t HISTB_SZ = 257ull * 131072ull;                 // 33,685,504
  const size_t OFF_XG  = 0;                                   // 134,217,728
  const size_t OFF_HA  = OFF_XG + (size_t)512 * 16384 * 8 * 2;// histA; slots 0-255 alias xb
  const size_t OFF_HB  = OFF_HA + HISTB_SZ;
  const size_t OFF_WIH = OFF_HB + HISTB_SZ;
  const size_t OFF_WHH = OFF_WIH + (size_t)2 * GDIM * HDIM * 2;
  const size_t OFF_SYNC= OFF_WHH + (size_t)2 * GDIM * HDIM * 2;

  bf16* xg    = (bf16*)(ws + OFF_XG);
  bf16* xb    = (bf16*)(ws + OFF_HA);   // embeddings = histA slots 0-255
  bf16* histA = (bf16*)(ws + OFF_HA);
  bf16* histB = (bf16*)(ws + OFF_HB);
  bf16* wihb  = (bf16*)(ws + OFF_WIH);
  bf16* whhb  = (bf16*)(ws + OFF_WHH);
  unsigned* sync = (unsigned*)(ws + OFF_SYNC);
  unsigned* fL1 = sync;                 // 4 bg x 256 u32
  unsigned* fL2 = sync + 1024;          // 4 bg x 128 u32

  (void)hipMemsetAsync(sync, 0, 16384, stream);
  (void)hipMemsetAsync(ws + OFF_HA + 33554432ull, 0, 131072, stream);  // histA slot 256 (h1(0)=0)
  (void)hipMemsetAsync(ws + OFF_HB + 33554432ull, 0, 131072, stream);  // histB slot 256 (h2(0)=0)

  const int nconv4 = 2 * GDIM * HDIM / 4;
  convert_bf16_kernel<<<nconv4 / 256, 256, 0, stream>>>(Wih, wihb, nconv4);
  convert_bf16_kernel<<<nconv4 / 256, 256, 0, stream>>>(Whh, whhb, nconv4);
  const int nemb4 = BATCH * TSTEPS * HDIM / 4;
  embed_kernel<<<nemb4 / 256, 256, 0, stream>>>(ids, table, xb, nemb4);

  float* out_last   = out;              // (64,1024)
  float* out_logits = out + 65536;      // (64,32000)
  float* out_hn     = out + 2113536;    // (2,64,1024)
  float* out_cn     = out + 2244608;    // (2,64,1024)

  gemm_xg_kernel<<<dim3(GDIM / BNX, (BATCH * TSTEPS) / BMX), 256, 0, stream>>>(
      xb, wihb, bih, bhh, xg);

  fused2_kernel<<<768, 256, 0, stream>>>(
      xg, whhb, whhb + (size_t)GDIM * HDIM, wihb + (size_t)GDIM * HDIM,
      bih + GDIM, bhh + GDIM, histA, histB,
      out_hn, out_cn, out_hn + BATCH * HDIM, out_cn + BATCH * HDIM, out_last,
      fL1, fL2);

  logits_kernel<<<VOCAB / 64, 256, 0, stream>>>(histB, Wp, bp, out_logits);
}

// Round 11
// 2175.441 us; speedup vs baseline: 1.5350x; 1.5350x over previous
//
#include <hip/hip_runtime.h>
#include <hip/hip_bf16.h>
#include <stdint.h>
#include <stddef.h>

typedef __hip_bfloat16 bf16;
typedef __attribute__((ext_vector_type(8))) short bfrag;
typedef __attribute__((ext_vector_type(4))) float ffrag;
typedef unsigned long long u64;

#define HDIM 1024
#define BATCH 64
#define TSTEPS 256
#define GDIM 4096
#define VOCAB 32000

// xg: ((q*128 + g)*16384 + idx)*8 + jj ; layer1 idx = b*256+t, layer2 idx = t*64+b
// h-history: 257 slots x 128 KB; slot (256-t) = h INPUT to step t (write-once).
//   u64 index within slot: half*8192 + kg*64 + b   (hidden k = kg*8 + half*4 + jj)
#define HSLOT 16384ull

__device__ __forceinline__ bf16 f2b(float x) { return __float2bfloat16(x); }
__device__ __forceinline__ short f2bs(float x) {
  bf16 b = __float2bfloat16(x);
  return *reinterpret_cast<short*>(&b);
}
__device__ __forceinline__ float bs2f(unsigned short u) {
  union { unsigned int i; float f; } v;
  v.i = ((unsigned int)u) << 16;
  return v.f;
}
__device__ __forceinline__ ffrag mfma16(bfrag a, bfrag b, ffrag c) {
  return __builtin_amdgcn_mfma_f32_16x16x32_bf16(a, b, c, 0, 0, 0);
}
__device__ __forceinline__ float sigm(float x) { return 1.0f / (1.0f + __expf(-x)); }
__device__ __forceinline__ float tanhfast(float x) {
  float e = __expf(2.0f * x);
  return 1.0f - 2.0f / (e + 1.0f);
}

__device__ __forceinline__ void store_u16_agent(unsigned short* p, unsigned short v) {
  __hip_atomic_store(p, v, __ATOMIC_RELAXED, __HIP_MEMORY_SCOPE_AGENT);
}
__device__ __forceinline__ unsigned load_u32_agent(const unsigned* p) {
  return __hip_atomic_load(p, __ATOMIC_RELAXED, __HIP_MEMORY_SCOPE_AGENT);
}
__device__ __forceinline__ void store_u32_agent(unsigned* p, unsigned v) {
  __hip_atomic_store(p, v, __ATOMIC_RELAXED, __HIP_MEMORY_SCOPE_AGENT);
}

// ---------------- convert f32 -> bf16 ----------------
__global__ void convert_bf16_kernel(const float* __restrict__ src, bf16* __restrict__ dst, int n4) {
  int i = blockIdx.x * 256 + threadIdx.x;
  if (i >= n4) return;
  float4 v = reinterpret_cast<const float4*>(src)[i];
  ushort4 o;
  o.x = (unsigned short)f2bs(v.x);
  o.y = (unsigned short)f2bs(v.y);
  o.z = (unsigned short)f2bs(v.z);
  o.w = (unsigned short)f2bs(v.w);
  reinterpret_cast<ushort4*>(dst)[i] = o;
}

// ---------------- embedding gather -> bf16 (rows m = b*256 + t) ----------------
__global__ void embed_kernel(const int* __restrict__ ids, const float* __restrict__ table,
                             bf16* __restrict__ x, int n4) {
  int i = blockIdx.x * 256 + threadIdx.x;
  if (i >= n4) return;
  int row = i >> 8;
  int c4 = i & 255;
  int tok = ids[row];
  float4 v = reinterpret_cast<const float4*>(table)[(size_t)tok * 256 + c4];
  ushort4 o;
  o.x = (unsigned short)f2bs(v.x);
  o.y = (unsigned short)f2bs(v.y);
  o.z = (unsigned short)f2bs(v.z);
  o.w = (unsigned short)f2bs(v.w);
  reinterpret_cast<ushort4*>(x)[i] = o;
}

// ---------------- xg = x @ W_ih^T + b_ih + b_hh ----------------
#define BMX 128
#define BNX 128
#define BKX 64

template<int LYR>
__launch_bounds__(256, 2)
__global__ void gemm_xg_kernel(const bf16* __restrict__ A,
                               const bf16* __restrict__ W,
                               const float* __restrict__ bih,
                               const float* __restrict__ bhh,
                               bf16* __restrict__ xg) {
  __shared__ bf16 As[BMX][BKX + 8];
  __shared__ bf16 Bs[BNX][BKX + 8];
  const int n0 = blockIdx.x * BNX;
  const int m0 = blockIdx.y * BMX;
  const int tid = threadIdx.x;
  const int w = tid >> 6, l = tid & 63;
  const int wm = (w >> 1) * 64, wn = (w & 1) * 64;
  const int lr = l & 15, lk = (l >> 4) * 8;

  ffrag acc[4][4];
#pragma unroll
  for (int i = 0; i < 4; ++i)
#pragma unroll
    for (int j = 0; j < 4; ++j) acc[i][j] = ffrag{0.f, 0.f, 0.f, 0.f};

  const int sr = tid >> 1, sh = (tid & 1) * 32;
  for (int kb = 0; kb < HDIM; kb += BKX) {
    __syncthreads();
    {
      if (LYR == 0) {
        const uint4* ga = reinterpret_cast<const uint4*>(&A[(size_t)(m0 + sr) * HDIM + kb + sh]);
        uint4* la = reinterpret_cast<uint4*>(&As[sr][sh]);
        la[0] = ga[0]; la[1] = ga[1]; la[2] = ga[2]; la[3] = ga[3];
      } else {
        const u64* hb = (const u64*)A;
        const int m = m0 + sr;                    // t = m>>6, b = m&63
        const size_t tb = (size_t)(255 - (m >> 6)) * HSLOT + (m & 63);
        const int kg0 = (kb + sh) >> 3;
#pragma unroll
        for (int ii = 0; ii < 4; ++ii) {
          u64 lo = hb[tb + (size_t)(kg0 + ii) * 64];
          u64 hi = hb[tb + 8192 + (size_t)(kg0 + ii) * 64];
          *(u64*)&As[sr][sh + ii * 8]     = lo;
          *(u64*)&As[sr][sh + ii * 8 + 4] = hi;
        }
      }
      const uint4* gb = reinterpret_cast<const uint4*>(&W[(size_t)(n0 + sr) * HDIM + kb + sh]);
      uint4* lb = reinterpret_cast<uint4*>(&Bs[sr][sh]);
      lb[0] = gb[0]; lb[1] = gb[1]; lb[2] = gb[2]; lb[3] = gb[3];
    }
    __syncthreads();
#pragma unroll
    for (int ks = 0; ks < 2; ++ks) {
      const int ko = ks * 32 + lk;
      bfrag af[4], bfv[4];
#pragma unroll
      for (int i = 0; i < 4; ++i)
        af[i] = *reinterpret_cast<const bfrag*>(&As[wm + i * 16 + lr][ko]);
#pragma unroll
      for (int j = 0; j < 4; ++j)
        bfv[j] = *reinterpret_cast<const bfrag*>(&Bs[wn + j * 16 + lr][ko]);
#pragma unroll
      for (int i = 0; i < 4; ++i)
#pragma unroll
        for (int j = 0; j < 4; ++j)
          acc[i][j] = mfma16(af[i], bfv[j], acc[i][j]);
    }
  }
  const int rg = (l >> 4) * 4;
#pragma unroll
  for (int j = 0; j < 4; ++j) {
    const int n = n0 + wn + j * 16 + lr;
    const float bias = bih[n] + bhh[n];
    const int q = n >> 10, g = (n & 1023) >> 3, jj = n & 7;
    bf16* base = xg + (size_t)(q * 128 + g) * 16384 * 8 + jj;
#pragma unroll
    for (int i = 0; i < 4; ++i) {
#pragma unroll
      for (int r = 0; r < 4; ++r) {
        const int m = m0 + wm + i * 16 + rg + r;
        base[(size_t)m * 8] = f2b(acc[i][j][r] + bias);
      }
    }
  }
}

// ---------------- persistent LSTM recurrence ----------------
// 256 blocks x 256 thr (4 waves). Block (bg=id&3, cg16=id>>2): 16 batches x 16 cols.
// Waves (kh = w>>1 K-half, ch = w&1 col-half): 32 W_hh bfrags in registers.
// ONE flag per block (64/bg = 2 cachelines); all waves poll (coalesced, 2 lines);
// flag stored by tid0 after a syncthreads that certifies all waves' h-stores acked.
__launch_bounds__(256, 1)
__global__ void lstm_seq_kernel(const bf16* __restrict__ xg,
                                const bf16* __restrict__ Whh,  // (4096,1024) bf16
                                bf16* hist,                    // 257 x 128 KB slots
                                float* __restrict__ out_h,
                                float* __restrict__ out_c,
                                float* __restrict__ out_last,  // null except last layer
                                unsigned* __restrict__ flags,  // u32[4][64]
                                int xbs, int xts) {
  __shared__ float gxp[2][16][65];
  const int id = blockIdx.x;
  const int bg = id & 3, cg16 = id >> 2;
  const int tid = threadIdx.x;
  const int w = tid >> 6, l = tid & 63;
  const int lr = l & 15, lkg = l >> 4;
  const int kh = w >> 1, ch = w & 1;
  const int q = lr >> 2, jn = lr & 3;

  // --- W_hh fragments into registers (once): 2 col-sets x 16 k-steps ---
  bfrag breg0[16], breg1[16];
  {
    const int colbase = cg16 * 16 + ch * 8;
    const size_t r0 = ((size_t)q * HDIM + colbase + jn) * HDIM + kh * 512 + lkg * 8;
    const size_t r1 = ((size_t)q * HDIM + colbase + 4 + jn) * HDIM + kh * 512 + lkg * 8;
#pragma unroll
    for (int ks = 0; ks < 16; ++ks) {
      breg0[ks] = *reinterpret_cast<const bfrag*>(&Whh[r0 + ks * 32]);
      breg1[ks] = *reinterpret_cast<const bfrag*>(&Whh[r1 + ks * 32]);
    }
  }

  // elementwise identity: batch eb, col-local cl (all 256 threads)
  const int eb = tid & 15, cl = tid >> 4;
  const int b_glob = bg * 16 + eb;
  const int gpl = cg16 * 2 + (cl >> 3);   // xg plane / h-store kg
  const int xjj = cl & 7;
  const int shalf = (cl >> 2) & 1, sjj = cl & 3;
  float c = 0.0f;

  u64* hb = (u64*)hist;
  const size_t arow = (size_t)(kh * 64 + lkg) * 64 + bg * 16 + lr;
  const unsigned* fv = flags + bg * 64;
  const unsigned short* xgu = (const unsigned short*)xg;

  unsigned short xn[4];
#pragma unroll
  for (int qq = 0; qq < 4; ++qq)
    xn[qq] = xgu[(((size_t)qq * 128 + gpl) * 16384 + (size_t)b_glob * xbs) * 8 + xjj];

#pragma unroll 1
  for (int t = 0; t < TSTEPS; ++t) {
    if (t > 0) {
      const unsigned tt = (unsigned)t;
      for (;;) {
        unsigned f = load_u32_agent(&fv[l]);
        if (__all((int)(f >= tt))) break;
        __builtin_amdgcn_s_sleep(1);
      }
    }
    __builtin_amdgcn_sched_barrier(0);
    asm volatile("" ::: "memory");   // no hoisting of h loads above the poll

    const u64* hin = hb + (size_t)(TSTEPS - t) * HSLOT;
    ffrag a0 = ffrag{0.f, 0.f, 0.f, 0.f};
    ffrag a1 = ffrag{0.f, 0.f, 0.f, 0.f};
#pragma unroll
    for (int ks = 0; ks < 16; ++ks) {
      union { u64 u[2]; bfrag f; } au;
      au.u[0] = hin[arow + ks * 256];          // cached (write-once slots)
      au.u[1] = hin[8192 + arow + ks * 256];
      a0 = mfma16(au.f, breg0[ks], a0);
      a1 = mfma16(au.f, breg1[ks], a1);
    }
    {
      const int cb = ch * 8;
#pragma unroll
      for (int r = 0; r < 4; ++r) {
        gxp[kh][lkg * 4 + r][q * 16 + cb + jn]     = a0[r];
        gxp[kh][lkg * 4 + r][q * 16 + cb + 4 + jn] = a1[r];
      }
    }
    __syncthreads();   // gxp ready

    const float gi = gxp[0][eb][cl]      + gxp[1][eb][cl]      + bs2f(xn[0]);
    const float gf = gxp[0][eb][16 + cl] + gxp[1][eb][16 + cl] + bs2f(xn[1]);
    const float gg = gxp[0][eb][32 + cl] + gxp[1][eb][32 + cl] + bs2f(xn[2]);
    const float go = gxp[0][eb][48 + cl] + gxp[1][eb][48 + cl] + bs2f(xn[3]);
    c = sigm(gf) * c + sigm(gi) * tanhfast(gg);
    const float h = sigm(go) * tanhfast(c);

    // h(t+1) -> slot 255-t (sc1, coalesced u16 runs)
    u64* hout = hb + (size_t)(255 - t) * HSLOT;
    store_u16_agent((unsigned short*)(hout + (size_t)shalf * 8192 + gpl * 64 + b_glob) + sjj,
                    (unsigned short)f2bs(h));
    if (t == TSTEPS - 1) {
      const int col = cg16 * 16 + cl;
      out_h[(size_t)b_glob * HDIM + col] = h;
      out_c[(size_t)b_glob * HDIM + col] = c;
      if (out_last) out_last[(size_t)b_glob * HDIM + col] = h;
    }
    __builtin_amdgcn_s_waitcnt(0);   // own wave's h stores acked at coherence point
    __syncthreads();                 // all 4 waves acked
    if (t < TSTEPS - 1) {
      if (tid == 0) store_u32_agent(&flags[bg * 64 + cg16], (unsigned)(t + 1));
      // prefetch next step's xg (cached; overlaps flag propagation)
#pragma unroll
      for (int qq = 0; qq < 4; ++qq)
        xn[qq] = xgu[(((size_t)qq * 128 + gpl) * 16384 +
                      (size_t)b_glob * xbs + (size_t)(t + 1) * xts) * 8 + xjj];
    }
    __builtin_amdgcn_sched_barrier(0);
  }
}

// ---------------- logits = h_T @ W_proj^T + b_proj ----------------
__launch_bounds__(256, 2)
__global__ void logits_kernel(const bf16* __restrict__ hfin,
                              const float* __restrict__ Wp,
                              const float* __restrict__ bp,
                              float* __restrict__ out) {
  const int tid = threadIdx.x;
  const int w = tid >> 6, l = tid & 63;
  const int lr = l & 15, lkg = l >> 4, lk = lkg * 8;
  const int col = blockIdx.x * 64 + w * 16 + lr;
  const float* wrow = &Wp[(size_t)col * HDIM];
  const u64* hb = (const u64*)hfin;
  ffrag acc[4];
#pragma unroll
  for (int i = 0; i < 4; ++i) acc[i] = ffrag{0.f, 0.f, 0.f, 0.f};
#pragma unroll 2
  for (int ks = 0; ks < 32; ++ks) {
    const int k = ks * 32 + lk;
    float4 wa = *reinterpret_cast<const float4*>(&wrow[k]);
    float4 wb = *reinterpret_cast<const float4*>(&wrow[k + 4]);
    bfrag bv;
    bv[0] = f2bs(wa.x); bv[1] = f2bs(wa.y); bv[2] = f2bs(wa.z); bv[3] = f2bs(wa.w);
    bv[4] = f2bs(wb.x); bv[5] = f2bs(wb.y); bv[6] = f2bs(wb.z); bv[7] = f2bs(wb.w);
    const size_t kg = (size_t)(ks * 4 + lkg);
#pragma unroll
    for (int i = 0; i < 4; ++i) {
      union { u64 u[2]; bfrag f; } av;
      av.u[0] = hb[kg * 64 + i * 16 + lr];
      av.u[1] = hb[8192 + kg * 64 + i * 16 + lr];
      acc[i] = mfma16(av.f, bv, acc[i]);
    }
  }
  const float bias = bp[col];
#pragma unroll
  for (int i = 0; i < 4; ++i) {
#pragma unroll
    for (int r = 0; r < 4; ++r) {
      const int b = i * 16 + (l >> 4) * 4 + r;
      out[(size_t)b * VOCAB + col] = acc[i][r] + bias;
    }
  }
}

extern "C" void kernel_launch(void* const* d_in, const int* in_sizes, int n_in,
                              void* d_out, int out_size, void* d_ws, size_t ws_size,
                              hipStream_t stream) {
  const int*   ids   = (const int*)d_in[0];
  const float* table = (const float*)d_in[1];
  const float* Wih   = (const float*)d_in[2];
  const float* Whh   = (const float*)d_in[3];
  const float* bih   = (const float*)d_in[4];
  const float* bhh   = (const float*)d_in[5];
  const float* Wp    = (const float*)d_in[6];
  const float* bp    = (const float*)d_in[7];
  float* out = (float*)d_out;

  char* ws = (char*)d_ws;
  const size_t HISTB_SZ = 257ull * 131072ull;                 // 33,685,504
  const size_t OFF_XG  = 0;                                   // 134,217,728
  const size_t OFF_HA  = OFF_XG + (size_t)512 * 16384 * 8 * 2;// histA; slots 0-255 alias xb
  const size_t OFF_HB  = OFF_HA + HISTB_SZ;
  const size_t OFF_WIH = OFF_HB + HISTB_SZ;
  const size_t OFF_WHH = OFF_WIH + (size_t)2 * GDIM * HDIM * 2;
  const size_t OFF_SYNC= OFF_WHH + (size_t)2 * GDIM * HDIM * 2;

  bf16* xg    = (bf16*)(ws + OFF_XG);
  bf16* xb    = (bf16*)(ws + OFF_HA);   // embeddings = histA slots 0-255
  bf16* histA = (bf16*)(ws + OFF_HA);
  bf16* histB = (bf16*)(ws + OFF_HB);
  bf16* wihb  = (bf16*)(ws + OFF_WIH);
  bf16* whhb  = (bf16*)(ws + OFF_WHH);
  unsigned* sync = (unsigned*)(ws + OFF_SYNC);

  (void)hipMemsetAsync(sync, 0, 16384, stream);
  (void)hipMemsetAsync(ws + OFF_HA + 33554432ull, 0, 131072, stream);  // histA slot 256
  (void)hipMemsetAsync(ws + OFF_HB + 33554432ull, 0, 131072, stream);  // histB slot 256

  const int nconv4 = 2 * GDIM * HDIM / 4;
  convert_bf16_kernel<<<nconv4 / 256, 256, 0, stream>>>(Wih, wihb, nconv4);
  convert_bf16_kernel<<<nconv4 / 256, 256, 0, stream>>>(Whh, whhb, nconv4);
  const int nemb4 = BATCH * TSTEPS * HDIM / 4;
  embed_kernel<<<nemb4 / 256, 256, 0, stream>>>(ids, table, xb, nemb4);

  float* out_last   = out;              // (64,1024)
  float* out_logits = out + 65536;      // (64,32000)
  float* out_hn     = out + 2113536;    // (2,64,1024)
  float* out_cn     = out + 2244608;    // (2,64,1024)

  // ---- layer 1 ----
  gemm_xg_kernel<0><<<dim3(GDIM / BNX, (BATCH * TSTEPS) / BMX), 256, 0, stream>>>(
      xb, wihb, bih, bhh, xg);
  lstm_seq_kernel<<<256, 256, 0, stream>>>(
      xg, whhb, histA, out_hn, out_cn, nullptr, sync, 256, 1);

  // ---- layer 2 ----
  gemm_xg_kernel<1><<<dim3(GDIM / BNX, (BATCH * TSTEPS) / BMX), 256, 0, stream>>>(
      histA, wihb + (size_t)GDIM * HDIM, bih + GDIM, bhh + GDIM, xg);
  lstm_seq_kernel<<<256, 256, 0, stream>>>(
      xg, whhb + (size_t)GDIM * HDIM, histB,
      out_hn + (size_t)BATCH * HDIM, out_cn + (size_t)BATCH * HDIM,
      out_last, sync + 256, 1, 64);

  logits_kernel<<<VOCAB / 64, 256, 0, stream>>>(histB, Wp, bp, out_logits);
}